// Round 3
// baseline (139.610 us; speedup 1.0000x reference)
//
#include <hip/hip_runtime.h>
#include <math.h>

namespace {

constexpr int B = 32, T = 4096, I = 16, O = 16;
constexpr int BOI = B * O * I; // 8192 = 2^13

__device__ __forceinline__ void channel_params(const float* __restrict__ bc,
                                               const float* __restrict__ rho,
                                               const float* __restrict__ psi,
                                               int o, int i,
                                               float& b0, float& b1, float& a1, float& a2) {
    int oi = o * I + i;
    b0 = bc[oi * 2 + 0];
    b1 = bc[oi * 2 + 1];
    float r     = 1.0f / (1.0f + expf(-rho[oi]));
    float theta = 3.14159265358979323846f / (1.0f + expf(-psi[oi]));
    a1 = -2.0f * r * cosf(theta);
    a2 = r * r;
}

// Pass 1: one thread per (b,o,i,chunk). Run chunk with zero IC, store the
// end state (y[last], y[last-1]) into d1/d2 at [k][boi]. Coalesced stores.
template <int L>
__global__ void pass1_kernel(const float* __restrict__ u, const float* __restrict__ bc,
                             const float* __restrict__ rho, const float* __restrict__ psi,
                             float* __restrict__ d1, float* __restrict__ d2) {
    int g = blockIdx.x * blockDim.x + threadIdx.x; // B*O*I*C threads
    int i = g & 15, o = (g >> 4) & 15, b = (g >> 8) & 31, k = g >> 13;
    float b0, b1, a1, a2;
    channel_params(bc, rho, psi, o, i, b0, b1, a1, a2);
    float na1 = -a1, na2 = -a2;
    int t0 = k * L;
    const float* up = u + (b * T + t0) * I + i;
    float uprev = (k == 0) ? 0.0f : up[-I];
    float y1 = 0.0f, y2 = 0.0f;
#pragma unroll
    for (int t = 0; t < L; ++t) {
        float uc = up[t * I];
        float x = fmaf(b1, uprev, b0 * uc);
        float y = fmaf(na2, y2, fmaf(na1, y1, x));
        y2 = y1; y1 = y; uprev = uc;
    }
    int idx = k * BOI + (g & (BOI - 1));
    d1[idx] = y1;
    d2[idx] = y2;
}

// Parallel affine scan (Hillis-Steele) over the C chunk end-states per
// channel. Operator: s_k = A_L * s_{k-1} + e_k, A_L = M^L constant per
// channel, so A_L^(2^p) is locally computable by squaring — log2(C) LDS
// rounds. Block = CH channels x C chunks (CH = 1024/C). In-place rewrite:
// slot k becomes the INCOMING state of chunk k (exclusive prefix). Safe
// in-place because one block owns all C chunks of its channels: all global
// loads precede the first barrier, all global stores follow the last.
template <int C, int L>
__global__ void scan_kernel(const float* __restrict__ bc, const float* __restrict__ rho,
                            const float* __restrict__ psi,
                            float* __restrict__ d1, float* __restrict__ d2) {
    constexpr int CH = 1024 / C;
    __shared__ float s1[2][C * CH];
    __shared__ float s2[2][C * CH];
    int tid = threadIdx.x;          // 0 .. C*CH-1
    int c = tid % CH;
    int k = tid / CH;               // chunk index
    int ch = blockIdx.x * CH + c;   // global channel in [0, BOI)
    int i = ch & 15, o = (ch >> 4) & 15;
    float b0, b1, a1, a2;
    channel_params(bc, rho, psi, o, i, b0, b1, a1, a2);
    // A_L = M^L via repeated squaring (L is a power of two)
    float m00 = -a1, m01 = -a2, m10 = 1.0f, m11 = 0.0f;
    for (int e = L; e > 1; e >>= 1) {
        float t00 = m00 * m00 + m01 * m10;
        float t01 = m00 * m01 + m01 * m11;
        float t10 = m10 * m00 + m11 * m10;
        float t11 = m10 * m01 + m11 * m11;
        m00 = t00; m01 = t01; m10 = t10; m11 = t11;
    }
    int gidx = k * BOI + ch;
    float vx = d1[gidx], vy = d2[gidx];
    int cur = 0;
    s1[0][tid] = vx; s2[0][tid] = vy;
    __syncthreads();
#pragma unroll
    for (int off = 1; off < C; off <<= 1) {
        float nx = 0.0f, ny = 0.0f;
        if (k >= off) {
            nx = s1[cur][tid - off * CH];
            ny = s2[cur][tid - off * CH];
        }
        vx += m00 * nx + m01 * ny;   // v += A_p * neighbor
        vy += m10 * nx + m11 * ny;
        cur ^= 1;
        s1[cur][tid] = vx; s2[cur][tid] = vy;
        // A_{p+1} = A_p^2
        float t00 = m00 * m00 + m01 * m10;
        float t01 = m00 * m01 + m01 * m11;
        float t10 = m10 * m00 + m11 * m10;
        float t11 = m10 * m01 + m11 * m11;
        m00 = t00; m01 = t01; m10 = t10; m11 = t11;
        __syncthreads();
    }
    if (k == 0) { d1[ch] = 0.0f; d2[ch] = 0.0f; }
    if (k + 1 < C) {
        d1[(k + 1) * BOI + ch] = vx;
        d2[(k + 1) * BOI + ch] = vy;
    }
}

// Pass 2: one thread per (b,o,i-half,chunk), 8 input channels per thread.
// 8 independent recurrence chains give ILP; the i-sum is 7 in-register adds
// + ONE __shfl_xor with the partner lane (vs 4 shuffles/t before — the DS
// pipe was the bottleneck). h==0 lanes store out[b,t,o] (o-contiguous).
template <int C, int L>
__global__ void pass2_kernel(const float* __restrict__ u, const float* __restrict__ bc,
                             const float* __restrict__ rho, const float* __restrict__ psi,
                             const float* __restrict__ d1, const float* __restrict__ d2,
                             float* __restrict__ out) {
    int g = blockIdx.x * blockDim.x + threadIdx.x; // B*O*2*C threads
    int h = g & 1, o = (g >> 1) & 15, b = (g >> 5) & 31, k = g >> 10;
    int i0 = h * 8;
    float b0[8], b1[8], na1[8], na2[8], y1[8], y2[8], uprev[8];
#pragma unroll
    for (int j = 0; j < 8; ++j) {
        float B0, B1, A1, A2;
        channel_params(bc, rho, psi, o, i0 + j, B0, B1, A1, A2);
        b0[j] = B0; b1[j] = B1; na1[j] = -A1; na2[j] = -A2;
    }
    int base = (b * O + o) * I + i0;          // multiple of 8 -> float4 aligned
    const float4* dv1 = (const float4*)(d1 + k * BOI + base);
    const float4* dv2 = (const float4*)(d2 + k * BOI + base);
    float4 p0 = dv1[0], p1 = dv1[1];
    float4 q0 = dv2[0], q1 = dv2[1];
    y1[0] = p0.x; y1[1] = p0.y; y1[2] = p0.z; y1[3] = p0.w;
    y1[4] = p1.x; y1[5] = p1.y; y1[6] = p1.z; y1[7] = p1.w;
    y2[0] = q0.x; y2[1] = q0.y; y2[2] = q0.z; y2[3] = q0.w;
    y2[4] = q1.x; y2[5] = q1.y; y2[6] = q1.z; y2[7] = q1.w;

    int t0 = k * L;
    const float* ubase = u + ((size_t)b * T + t0) * I + i0;
    if (k == 0) {
#pragma unroll
        for (int j = 0; j < 8; ++j) uprev[j] = 0.0f;
    } else {
        const float4* pv = (const float4*)(ubase - I);
        float4 r0 = pv[0], r1 = pv[1];
        uprev[0] = r0.x; uprev[1] = r0.y; uprev[2] = r0.z; uprev[3] = r0.w;
        uprev[4] = r1.x; uprev[5] = r1.y; uprev[6] = r1.z; uprev[7] = r1.w;
    }
    float* op = out + ((size_t)b * T + t0) * O + o;
    bool writer = (h == 0);
#pragma unroll
    for (int t = 0; t < L; ++t) {
        const float4* row = (const float4*)(ubase + t * I);
        float4 a = row[0], c = row[1];
        float uc[8];
        uc[0] = a.x; uc[1] = a.y; uc[2] = a.z; uc[3] = a.w;
        uc[4] = c.x; uc[5] = c.y; uc[6] = c.z; uc[7] = c.w;
        float yv[8];
#pragma unroll
        for (int j = 0; j < 8; ++j) {
            float x = fmaf(b1[j], uprev[j], b0[j] * uc[j]);
            float y = fmaf(na2[j], y2[j], fmaf(na1[j], y1[j], x));
            y2[j] = y1[j]; y1[j] = y; uprev[j] = uc[j];
            yv[j] = y;
        }
        float s01 = yv[0] + yv[1], s23 = yv[2] + yv[3];
        float s45 = yv[4] + yv[5], s67 = yv[6] + yv[7];
        float s = (s01 + s23) + (s45 + s67);
        s += __shfl_xor(s, 1);
        if (writer) op[t * O] = s;
    }
}

template <int C>
void launch_all(const float* u, const float* bc, const float* rho, const float* psi,
                float* d1, float* d2, float* out, hipStream_t stream) {
    constexpr int L = T / C;
    pass1_kernel<L><<<dim3((B * O * I * C) / 256), dim3(256), 0, stream>>>(
        u, bc, rho, psi, d1, d2);
    scan_kernel<C, L><<<dim3(BOI / (1024 / C)), dim3(1024), 0, stream>>>(
        bc, rho, psi, d1, d2);
    pass2_kernel<C, L><<<dim3((B * O * 2 * C) / 256), dim3(256), 0, stream>>>(
        u, bc, rho, psi, d1, d2, out);
}

} // namespace

extern "C" void kernel_launch(void* const* d_in, const int* in_sizes, int n_in,
                              void* d_out, int out_size, void* d_ws, size_t ws_size,
                              hipStream_t stream) {
    const float* u   = (const float*)d_in[0];
    const float* bc  = (const float*)d_in[1];
    const float* rho = (const float*)d_in[2];
    const float* psi = (const float*)d_in[3];
    float* out = (float*)d_out;

    // Largest chunk count C whose workspace (C*BOI*2 floats) fits.
    int C = 256;
    while (C > 64 && (size_t)C * BOI * 2 * sizeof(float) > ws_size) C >>= 1;

    float* d1 = (float*)d_ws;
    float* d2 = d1 + (size_t)C * BOI;

    if (C == 256)      launch_all<256>(u, bc, rho, psi, d1, d2, out, stream);
    else if (C == 128) launch_all<128>(u, bc, rho, psi, d1, d2, out, stream);
    else               launch_all<64> (u, bc, rho, psi, d1, d2, out, stream);
}

// Round 4
// 97.083 us; speedup vs baseline: 1.4381x; 1.4381x over previous
//
#include <hip/hip_runtime.h>
#include <math.h>

namespace {

constexpr int B = 32, T = 4096, I = 16, O = 16;
constexpr int BOI = B * O * I; // 8192

__device__ __forceinline__ void channel_params(const float* __restrict__ bc,
                                               const float* __restrict__ rho,
                                               const float* __restrict__ psi,
                                               int o, int i,
                                               float& b0, float& b1, float& a1, float& a2) {
    int oi = o * I + i;
    b0 = bc[oi * 2 + 0];
    b1 = bc[oi * 2 + 1];
    float r     = 1.0f / (1.0f + expf(-rho[oi]));
    float theta = 3.14159265358979323846f / (1.0f + expf(-psi[oi]));
    a1 = -2.0f * r * cosf(theta);
    a2 = r * r;
}

// Fused pass1 + scan. One block per (b,o): 16 i-channels x (C/2) segments of
// 2 chunks each. Thread (i, kp) runs SEG=2L recurrence steps with zero AR IC
// (real uprev), forms the segment's affine offset E = M^L*e0 + e1, then a
// log2(C/2)-round LDS Hillis-Steele scan (matrices M^(SEG*2^p) are local
// squarings since M is channel-constant) yields each chunk's exact incoming
// state, stored to d1/d2[k*BOI + ch]. No scan kernel, no state re-read.
// Wave = 16 i x 4 kp: u loads are 4 fully-used 64B lines; d writes coalesced.
template <int C>
__global__ void state_kernel(const float* __restrict__ u, const float* __restrict__ bc,
                             const float* __restrict__ rho, const float* __restrict__ psi,
                             float* __restrict__ d1, float* __restrict__ d2) {
    constexpr int L = T / C;       // chunk length
    constexpr int KP = C / 2;      // segments per channel
    constexpr int SEG = 2 * L;
    __shared__ float s1[2][KP * 16];
    __shared__ float s2[2][KP * 16];
    int tid = threadIdx.x;         // 16*KP threads
    int il = tid & 15;             // i
    int kp = tid >> 4;             // segment index
    int blk = blockIdx.x;          // b*O + o
    int o = blk & 15, b = blk >> 4;
    float b0, b1, a1, a2;
    channel_params(bc, rho, psi, o, il, b0, b1, a1, a2);
    float na1 = -a1, na2 = -a2;

    int t0 = kp * SEG;
    const float* up = u + ((size_t)(b * T + t0)) * I + il;
    float uprev = (kp == 0) ? 0.0f : up[-I];

    // zero-IC end state of chunk k0 = 2*kp
    float y1 = 0.0f, y2 = 0.0f;
#pragma unroll
    for (int t = 0; t < L; ++t) {
        float uc = up[t * I];
        float x = fmaf(b1, uprev, b0 * uc);
        float y = fmaf(na2, y2, fmaf(na1, y1, x));
        y2 = y1; y1 = y; uprev = uc;
    }
    float e0x = y1, e0y = y2;
    // zero-IC end state of chunk k1 = 2*kp+1 (uprev stays continuous)
    y1 = 0.0f; y2 = 0.0f;
#pragma unroll
    for (int t = L; t < SEG; ++t) {
        float uc = up[t * I];
        float x = fmaf(b1, uprev, b0 * uc);
        float y = fmaf(na2, y2, fmaf(na1, y1, x));
        y2 = y1; y1 = y; uprev = uc;
    }
    float e1x = y1, e1y = y2;

    // PL = M^L via repeated squaring (L power of two), M = [[-a1,-a2],[1,0]]
    float m00 = na1, m01 = na2, m10 = 1.0f, m11 = 0.0f;
#pragma unroll
    for (int e = L; e > 1; e >>= 1) {
        float t00 = m00 * m00 + m01 * m10;
        float t01 = m00 * m01 + m01 * m11;
        float t10 = m10 * m00 + m11 * m10;
        float t11 = m10 * m01 + m11 * m11;
        m00 = t00; m01 = t01; m10 = t10; m11 = t11;
    }
    float pl00 = m00, pl01 = m01, pl10 = m10, pl11 = m11; // save M^L
    // segment offset E = PL*e0 + e1
    float Ex = pl00 * e0x + pl01 * e0y + e1x;
    float Ey = pl10 * e0x + pl11 * e0y + e1y;
    // advance to M^SEG for the scan
    {
        float t00 = m00 * m00 + m01 * m10;
        float t01 = m00 * m01 + m01 * m11;
        float t10 = m10 * m00 + m11 * m10;
        float t11 = m10 * m01 + m11 * m11;
        m00 = t00; m01 = t01; m10 = t10; m11 = t11;
    }

    // Hillis-Steele inclusive scan over KP segments (per channel column)
    int cur = 0;
    s1[0][tid] = Ex; s2[0][tid] = Ey;
    __syncthreads();
#pragma unroll
    for (int off = 1; off < KP; off <<= 1) {
        float nx = 0.0f, ny = 0.0f;
        if (kp >= off) {
            nx = s1[cur][tid - off * 16];
            ny = s2[cur][tid - off * 16];
        }
        Ex += m00 * nx + m01 * ny;
        Ey += m10 * nx + m11 * ny;
        cur ^= 1;
        s1[cur][tid] = Ex; s2[cur][tid] = Ey;
        float t00 = m00 * m00 + m01 * m10;
        float t01 = m00 * m01 + m01 * m11;
        float t10 = m10 * m00 + m11 * m10;
        float t11 = m10 * m01 + m11 * m11;
        m00 = t00; m01 = t01; m10 = t10; m11 = t11;
        __syncthreads();
    }
    // incoming state of this segment = inclusive prefix of segment kp-1
    float Sx = 0.0f, Sy = 0.0f;
    if (kp > 0) { Sx = s1[cur][tid - 16]; Sy = s2[cur][tid - 16]; }

    int ch = blk * 16 + il;  // global channel (b*O+o)*I + i
    int k0 = 2 * kp;
    d1[(size_t)k0 * BOI + ch] = Sx;
    d2[(size_t)k0 * BOI + ch] = Sy;
    // incoming state of chunk k1 = PL*S + e0
    float S1x = pl00 * Sx + pl01 * Sy + e0x;
    float S1y = pl10 * Sx + pl11 * Sy + e0y;
    d1[(size_t)(k0 + 1) * BOI + ch] = S1x;
    d2[(size_t)(k0 + 1) * BOI + ch] = S1y;
}

// Pass 2: one thread per (b,o,i-half,chunk), 8 input channels per thread.
// 8 independent recurrence chains for ILP; i-sum = 7 in-register adds + one
// __shfl_xor; h==0 lanes store out[b,t,o] (o-contiguous, fully-used lines).
template <int C>
__global__ void pass2_kernel(const float* __restrict__ u, const float* __restrict__ bc,
                             const float* __restrict__ rho, const float* __restrict__ psi,
                             const float* __restrict__ d1, const float* __restrict__ d2,
                             float* __restrict__ out) {
    constexpr int L = T / C;
    int g = blockIdx.x * blockDim.x + threadIdx.x; // B*O*2*C threads
    int h = g & 1, o = (g >> 1) & 15, b = (g >> 5) & 31, k = g >> 10;
    int i0 = h * 8;
    float b0[8], b1[8], na1[8], na2[8], y1[8], y2[8], uprev[8];
#pragma unroll
    for (int j = 0; j < 8; ++j) {
        float B0, B1, A1, A2;
        channel_params(bc, rho, psi, o, i0 + j, B0, B1, A1, A2);
        b0[j] = B0; b1[j] = B1; na1[j] = -A1; na2[j] = -A2;
    }
    int base = (b * O + o) * I + i0;
    const float4* dv1 = (const float4*)(d1 + (size_t)k * BOI + base);
    const float4* dv2 = (const float4*)(d2 + (size_t)k * BOI + base);
    float4 p0 = dv1[0], p1 = dv1[1];
    float4 q0 = dv2[0], q1 = dv2[1];
    y1[0] = p0.x; y1[1] = p0.y; y1[2] = p0.z; y1[3] = p0.w;
    y1[4] = p1.x; y1[5] = p1.y; y1[6] = p1.z; y1[7] = p1.w;
    y2[0] = q0.x; y2[1] = q0.y; y2[2] = q0.z; y2[3] = q0.w;
    y2[4] = q1.x; y2[5] = q1.y; y2[6] = q1.z; y2[7] = q1.w;

    int t0 = k * L;
    const float* ubase = u + ((size_t)b * T + t0) * I + i0;
    if (k == 0) {
#pragma unroll
        for (int j = 0; j < 8; ++j) uprev[j] = 0.0f;
    } else {
        const float4* pv = (const float4*)(ubase - I);
        float4 r0 = pv[0], r1 = pv[1];
        uprev[0] = r0.x; uprev[1] = r0.y; uprev[2] = r0.z; uprev[3] = r0.w;
        uprev[4] = r1.x; uprev[5] = r1.y; uprev[6] = r1.z; uprev[7] = r1.w;
    }
    float* op = out + ((size_t)b * T + t0) * O + o;
    bool writer = (h == 0);
#pragma unroll
    for (int t = 0; t < L; ++t) {
        const float4* row = (const float4*)(ubase + t * I);
        float4 a = row[0], c = row[1];
        float uc[8];
        uc[0] = a.x; uc[1] = a.y; uc[2] = a.z; uc[3] = a.w;
        uc[4] = c.x; uc[5] = c.y; uc[6] = c.z; uc[7] = c.w;
        float yv[8];
#pragma unroll
        for (int j = 0; j < 8; ++j) {
            float x = fmaf(b1[j], uprev[j], b0[j] * uc[j]);
            float y = fmaf(na2[j], y2[j], fmaf(na1[j], y1[j], x));
            y2[j] = y1[j]; y1[j] = y; uprev[j] = uc[j];
            yv[j] = y;
        }
        float s01 = yv[0] + yv[1], s23 = yv[2] + yv[3];
        float s45 = yv[4] + yv[5], s67 = yv[6] + yv[7];
        float s = (s01 + s23) + (s45 + s67);
        s += __shfl_xor(s, 1);
        if (writer) op[t * O] = s;
    }
}

template <int C>
void launch_all(const float* u, const float* bc, const float* rho, const float* psi,
                float* d1, float* d2, float* out, hipStream_t stream) {
    state_kernel<C><<<dim3(B * O), dim3(16 * (C / 2)), 0, stream>>>(
        u, bc, rho, psi, d1, d2);
    pass2_kernel<C><<<dim3((B * O * 2 * C) / 256), dim3(256), 0, stream>>>(
        u, bc, rho, psi, d1, d2, out);
}

} // namespace

extern "C" void kernel_launch(void* const* d_in, const int* in_sizes, int n_in,
                              void* d_out, int out_size, void* d_ws, size_t ws_size,
                              hipStream_t stream) {
    const float* u   = (const float*)d_in[0];
    const float* bc  = (const float*)d_in[1];
    const float* rho = (const float*)d_in[2];
    const float* psi = (const float*)d_in[3];
    float* out = (float*)d_out;

    // Chunk count C=128: ws need = C*BOI*2 floats = 8 MB. Fallback halves C.
    int C = 128;
    while (C > 32 && (size_t)C * BOI * 2 * sizeof(float) > ws_size) C >>= 1;

    float* d1 = (float*)d_ws;
    float* d2 = d1 + (size_t)C * BOI;

    if (C == 128)      launch_all<128>(u, bc, rho, psi, d1, d2, out, stream);
    else if (C == 64)  launch_all<64> (u, bc, rho, psi, d1, d2, out, stream);
    else               launch_all<32> (u, bc, rho, psi, d1, d2, out, stream);
}

// Round 5
// 94.482 us; speedup vs baseline: 1.4776x; 1.0275x over previous
//
#include <hip/hip_runtime.h>
#include <math.h>

namespace {

constexpr int B = 32, T = 4096, I = 16, O = 16;
constexpr int BOI = B * O * I; // 8192

__device__ __forceinline__ void channel_params(const float* __restrict__ bc,
                                               const float* __restrict__ rho,
                                               const float* __restrict__ psi,
                                               int o, int i,
                                               float& b0, float& b1, float& a1, float& a2) {
    int oi = o * I + i;
    b0 = bc[oi * 2 + 0];
    b1 = bc[oi * 2 + 1];
    float r     = 1.0f / (1.0f + expf(-rho[oi]));
    float theta = 3.14159265358979323846f / (1.0f + expf(-psi[oi]));
    a1 = -2.0f * r * cosf(theta);
    a2 = r * r;
}

// Fused pass1 + scan. One block per (b,o): 16 i-channels x (C/2) segments of
// 2 chunks each. Thread (i, kp) runs SEG=2L recurrence steps with zero AR IC
// (real uprev), forms the segment's affine offset, then a log2(C/2)-round LDS
// Hillis-Steele scan yields each chunk's exact incoming state -> d1/d2.
// blockIdx decode is b = blk&31, o = blk>>5: under round-robin XCD dispatch
// (xcd ~ blockIdx%8) all 16 o-blocks sharing u[b] land on ONE XCD, so the
// 16x-redundant u[b] read (256KB x16) is served by that XCD's L2, not L3.
template <int C>
__global__ void state_kernel(const float* __restrict__ u, const float* __restrict__ bc,
                             const float* __restrict__ rho, const float* __restrict__ psi,
                             float* __restrict__ d1, float* __restrict__ d2) {
    constexpr int L = T / C;       // chunk length
    constexpr int KP = C / 2;      // segments per channel
    constexpr int SEG = 2 * L;
    __shared__ float s1[2][KP * 16];
    __shared__ float s2[2][KP * 16];
    int tid = threadIdx.x;         // 16*KP threads
    int il = tid & 15;             // i
    int kp = tid >> 4;             // segment index
    int blk = blockIdx.x;
    int b = blk & 31, o = blk >> 5;   // same-b blocks contiguous mod 8 -> same XCD
    float b0, b1, a1, a2;
    channel_params(bc, rho, psi, o, il, b0, b1, a1, a2);
    float na1 = -a1, na2 = -a2;

    int t0 = kp * SEG;
    const float* up = u + ((size_t)(b * T + t0)) * I + il;
    float uprev = (kp == 0) ? 0.0f : up[-I];

    // zero-IC end state of chunk k0 = 2*kp
    float y1 = 0.0f, y2 = 0.0f;
#pragma unroll
    for (int t = 0; t < L; ++t) {
        float uc = up[t * I];
        float x = fmaf(b1, uprev, b0 * uc);
        float y = fmaf(na2, y2, fmaf(na1, y1, x));
        y2 = y1; y1 = y; uprev = uc;
    }
    float e0x = y1, e0y = y2;
    // zero-IC end state of chunk k1 = 2*kp+1 (uprev stays continuous)
    y1 = 0.0f; y2 = 0.0f;
#pragma unroll
    for (int t = L; t < SEG; ++t) {
        float uc = up[t * I];
        float x = fmaf(b1, uprev, b0 * uc);
        float y = fmaf(na2, y2, fmaf(na1, y1, x));
        y2 = y1; y1 = y; uprev = uc;
    }
    float e1x = y1, e1y = y2;

    // PL = M^L via repeated squaring (L power of two), M = [[-a1,-a2],[1,0]]
    float m00 = na1, m01 = na2, m10 = 1.0f, m11 = 0.0f;
#pragma unroll
    for (int e = L; e > 1; e >>= 1) {
        float t00 = m00 * m00 + m01 * m10;
        float t01 = m00 * m01 + m01 * m11;
        float t10 = m10 * m00 + m11 * m10;
        float t11 = m10 * m01 + m11 * m11;
        m00 = t00; m01 = t01; m10 = t10; m11 = t11;
    }
    float pl00 = m00, pl01 = m01, pl10 = m10, pl11 = m11; // save M^L
    // segment offset E = PL*e0 + e1
    float Ex = pl00 * e0x + pl01 * e0y + e1x;
    float Ey = pl10 * e0x + pl11 * e0y + e1y;
    // advance to M^SEG for the scan
    {
        float t00 = m00 * m00 + m01 * m10;
        float t01 = m00 * m01 + m01 * m11;
        float t10 = m10 * m00 + m11 * m10;
        float t11 = m10 * m01 + m11 * m11;
        m00 = t00; m01 = t01; m10 = t10; m11 = t11;
    }

    // Hillis-Steele inclusive scan over KP segments (per channel column)
    int cur = 0;
    s1[0][tid] = Ex; s2[0][tid] = Ey;
    __syncthreads();
#pragma unroll
    for (int off = 1; off < KP; off <<= 1) {
        float nx = 0.0f, ny = 0.0f;
        if (kp >= off) {
            nx = s1[cur][tid - off * 16];
            ny = s2[cur][tid - off * 16];
        }
        Ex += m00 * nx + m01 * ny;
        Ey += m10 * nx + m11 * ny;
        cur ^= 1;
        s1[cur][tid] = Ex; s2[cur][tid] = Ey;
        float t00 = m00 * m00 + m01 * m10;
        float t01 = m00 * m01 + m01 * m11;
        float t10 = m10 * m00 + m11 * m10;
        float t11 = m10 * m01 + m11 * m11;
        m00 = t00; m01 = t01; m10 = t10; m11 = t11;
        __syncthreads();
    }
    // incoming state of this segment = inclusive prefix of segment kp-1
    float Sx = 0.0f, Sy = 0.0f;
    if (kp > 0) { Sx = s1[cur][tid - 16]; Sy = s2[cur][tid - 16]; }

    int ch = (b * O + o) * I + il;  // global channel index
    int k0 = 2 * kp;
    d1[(size_t)k0 * BOI + ch] = Sx;
    d2[(size_t)k0 * BOI + ch] = Sy;
    // incoming state of chunk k1 = PL*S + e0
    float S1x = pl00 * Sx + pl01 * Sy + e0x;
    float S1y = pl10 * Sx + pl11 * Sy + e0y;
    d1[(size_t)(k0 + 1) * BOI + ch] = S1x;
    d2[(size_t)(k0 + 1) * BOI + ch] = S1y;
}

// Pass 2: one thread per (b,o,i-quad,chunk), 4 input channels per thread.
// vs R4's 8-ch version: 2x the waves (4/SIMD grid-wide) to hide the 32-step
// 2-FMA dependence chain; i-sum = 3 in-register adds + two __shfl_xor (off
// the recurrence critical path). q==0 lanes store out[b,t,o]: 16 o-contiguous
// lanes -> one 64B line per wave store.
template <int C>
__global__ void pass2_kernel(const float* __restrict__ u, const float* __restrict__ bc,
                             const float* __restrict__ rho, const float* __restrict__ psi,
                             const float* __restrict__ d1, const float* __restrict__ d2,
                             float* __restrict__ out) {
    constexpr int L = T / C;
    int g = blockIdx.x * blockDim.x + threadIdx.x; // B*O*4*C threads
    int q = g & 3, o = (g >> 2) & 15, b = (g >> 6) & 31, k = g >> 11;
    int i0 = q * 4;
    float b0[4], b1[4], na1[4], na2[4], y1[4], y2[4], uprev[4];
#pragma unroll
    for (int j = 0; j < 4; ++j) {
        float B0, B1, A1, A2;
        channel_params(bc, rho, psi, o, i0 + j, B0, B1, A1, A2);
        b0[j] = B0; b1[j] = B1; na1[j] = -A1; na2[j] = -A2;
    }
    int base = (b * O + o) * I + i0;   // multiple of 4 -> float4 aligned
    float4 p0 = *(const float4*)(d1 + (size_t)k * BOI + base);
    float4 q0 = *(const float4*)(d2 + (size_t)k * BOI + base);
    y1[0] = p0.x; y1[1] = p0.y; y1[2] = p0.z; y1[3] = p0.w;
    y2[0] = q0.x; y2[1] = q0.y; y2[2] = q0.z; y2[3] = q0.w;

    int t0 = k * L;
    const float* ubase = u + ((size_t)b * T + t0) * I + i0;
    if (k == 0) {
#pragma unroll
        for (int j = 0; j < 4; ++j) uprev[j] = 0.0f;
    } else {
        float4 r0 = *(const float4*)(ubase - I);
        uprev[0] = r0.x; uprev[1] = r0.y; uprev[2] = r0.z; uprev[3] = r0.w;
    }
    float* op = out + ((size_t)b * T + t0) * O + o;
    bool writer = (q == 0);
#pragma unroll
    for (int t = 0; t < L; ++t) {
        float4 a = *(const float4*)(ubase + t * I);
        float uc[4];
        uc[0] = a.x; uc[1] = a.y; uc[2] = a.z; uc[3] = a.w;
        float yv[4];
#pragma unroll
        for (int j = 0; j < 4; ++j) {
            float x = fmaf(b1[j], uprev[j], b0[j] * uc[j]);
            float y = fmaf(na2[j], y2[j], fmaf(na1[j], y1[j], x));
            y2[j] = y1[j]; y1[j] = y; uprev[j] = uc[j];
            yv[j] = y;
        }
        float s = (yv[0] + yv[1]) + (yv[2] + yv[3]);
        s += __shfl_xor(s, 1);
        s += __shfl_xor(s, 2);
        if (writer) op[t * O] = s;
    }
}

template <int C>
void launch_all(const float* u, const float* bc, const float* rho, const float* psi,
                float* d1, float* d2, float* out, hipStream_t stream) {
    state_kernel<C><<<dim3(B * O), dim3(16 * (C / 2)), 0, stream>>>(
        u, bc, rho, psi, d1, d2);
    pass2_kernel<C><<<dim3((B * O * 4 * C) / 256), dim3(256), 0, stream>>>(
        u, bc, rho, psi, d1, d2, out);
}

} // namespace

extern "C" void kernel_launch(void* const* d_in, const int* in_sizes, int n_in,
                              void* d_out, int out_size, void* d_ws, size_t ws_size,
                              hipStream_t stream) {
    const float* u   = (const float*)d_in[0];
    const float* bc  = (const float*)d_in[1];
    const float* rho = (const float*)d_in[2];
    const float* psi = (const float*)d_in[3];
    float* out = (float*)d_out;

    // Chunk count C=128: ws need = C*BOI*2 floats = 8 MB. Fallback halves C.
    int C = 128;
    while (C > 32 && (size_t)C * BOI * 2 * sizeof(float) > ws_size) C >>= 1;

    float* d1 = (float*)d_ws;
    float* d2 = d1 + (size_t)C * BOI;

    if (C == 128)      launch_all<128>(u, bc, rho, psi, d1, d2, out, stream);
    else if (C == 64)  launch_all<64> (u, bc, rho, psi, d1, d2, out, stream);
    else               launch_all<32> (u, bc, rho, psi, d1, d2, out, stream);
}